// Round 15
// baseline (366.020 us; speedup 1.0000x reference)
//
#include <hip/hip_runtime.h>
#include <math.h>

#define DIM 128
#define NHEADS 4
#define GROWS 16

// ---------------------------------------------------------------------------
// K1: h_src = x @ W_src, h_dst = x @ W_dst   (fused; 16 x-rows per block)
// round-13: ROWS 8->16 to halve per-block W re-reads (W traffic 819->410 MB).
// LDS reads float4; unroll capped (round-4 lesson: full unroll -> spill).
// ---------------------------------------------------------------------------
__global__ __launch_bounds__(256) void k_dual_gemm(
    const float* __restrict__ x,
    const float* __restrict__ Wsrc, const float* __restrict__ Wdst,
    float* __restrict__ h_src, float* __restrict__ h_dst, int n)
{
    __shared__ float xs[GROWS][DIM];
    const int tid = threadIdx.x;
    const int r0 = blockIdx.x * GROWS;
    #pragma unroll
    for (int k = 0; k < GROWS * 32 / 256; ++k) {     // 2 float4s per thread
        int idx = k * 256 + tid;                      // 0..511
        int r = idx >> 5, c4 = idx & 31;
        int row = r0 + r;
        float4 v = make_float4(0.f, 0.f, 0.f, 0.f);
        if (row < n) v = ((const float4*)(x + (size_t)row * DIM))[c4];
        ((float4*)xs[r])[c4] = v;
    }
    __syncthreads();

    const int c = tid & 127;
    const float* __restrict__ W = (tid < 128) ? Wsrc : Wdst;
    float* __restrict__ H       = (tid < 128) ? h_src : h_dst;

    float acc[GROWS];
    #pragma unroll
    for (int r = 0; r < GROWS; ++r) acc[r] = 0.f;

    #pragma unroll 2
    for (int j4 = 0; j4 < DIM / 4; ++j4) {
        const float w0 = W[(4 * j4 + 0) * DIM + c];
        const float w1 = W[(4 * j4 + 1) * DIM + c];
        const float w2 = W[(4 * j4 + 2) * DIM + c];
        const float w3 = W[(4 * j4 + 3) * DIM + c];
        #pragma unroll
        for (int r = 0; r < GROWS; ++r) {
            const float4 xv = ((const float4*)xs[r])[j4];   // b128 broadcast
            acc[r] += xv.x * w0 + xv.y * w1 + xv.z * w2 + xv.w * w3;
        }
    }
    #pragma unroll
    for (int r = 0; r < GROWS; ++r) {
        if (r0 + r < n) H[(size_t)(r0 + r) * DIM + c] = acc[r];
    }
}

// ---------------------------------------------------------------------------
// CSR build: histogram -> multi-block scan (A/B/C) -> scatter
// ---------------------------------------------------------------------------
__global__ __launch_bounds__(256) void k_hist(
    const int* __restrict__ ei, int* __restrict__ deg, int E)
{
    int e = blockIdx.x * 256 + threadIdx.x;
    if (e < E) atomicAdd(&deg[ei[E + e]], 1);
}

__global__ __launch_bounds__(1024) void k_scanA(
    const int* __restrict__ deg, int* __restrict__ exc,
    int* __restrict__ bsum, int n)
{
    __shared__ int buf[1024];
    const int t = threadIdx.x;
    const int i = blockIdx.x * 1024 + t;
    int v = (i < n) ? deg[i] : 0;
    buf[t] = v;
    __syncthreads();
    #pragma unroll
    for (int off = 1; off < 1024; off <<= 1) {
        int u = (t >= off) ? buf[t - off] : 0;
        __syncthreads();
        buf[t] += u;
        __syncthreads();
    }
    if (i < n) exc[i] = buf[t] - v;          // exclusive within block
    if (t == 1023) bsum[blockIdx.x] = buf[1023];
}

__global__ __launch_bounds__(1024) void k_scanB(int* __restrict__ bsum, int nb)
{
    __shared__ int buf[1024];
    const int t = threadIdx.x;
    int v = (t < nb) ? bsum[t] : 0;
    buf[t] = v;
    __syncthreads();
    #pragma unroll
    for (int off = 1; off < 1024; off <<= 1) {
        int u = (t >= off) ? buf[t - off] : 0;
        __syncthreads();
        buf[t] += u;
        __syncthreads();
    }
    if (t < nb) bsum[t] = buf[t] - v;        // exclusive block offsets
}

__global__ __launch_bounds__(256) void k_scanC(
    const int* __restrict__ exc, const int* __restrict__ bsum,
    int* __restrict__ offs, int* __restrict__ cursor, int n, int E)
{
    int i = blockIdx.x * 256 + threadIdx.x;
    if (i < n) {
        int o = exc[i] + bsum[i >> 10];
        offs[i] = o;
        cursor[i] = o;
    }
    if (i == 0) offs[n] = E;
}

__global__ __launch_bounds__(256) void k_scatter(
    const int* __restrict__ ei, int* __restrict__ cursor,
    int* __restrict__ srcs, int E)
{
    int e = blockIdx.x * 256 + threadIdx.x;
    if (e >= E) return;
    int s = ei[e];
    int d = ei[E + e];
    int pos = atomicAdd(&cursor[d], 1);
    srcs[pos] = s;
}

// ---------------------------------------------------------------------------
// K2: pull-mode aggregation + residual + LayerNorm. One wave per node; each
// 32-lane half processes a PAIR of edges per iteration (4 edges in flight
// per wave — round-13 ILP/MLP change; independent shfl chains interleave).
// Lane l owns features 4l..4l+3; full-W_attn width-32 butterfly per edge
// (round-11 lesson: per-head partial reduce must span all 128 features).
// ---------------------------------------------------------------------------
__global__ __launch_bounds__(256) void k_aggregate(
    const int* __restrict__ offs, const int* __restrict__ srcs,
    const float* __restrict__ h_src, const float* __restrict__ h_dst,
    const float* __restrict__ W_attn,
    const float* __restrict__ gamma, const float* __restrict__ beta,
    float* __restrict__ out, int n)
{
    const int node = blockIdx.x * 4 + (threadIdx.x >> 6);
    if (node >= n) return;
    const int lane = threadIdx.x & 63;
    const int half = lane >> 5;       // half 0: edge pairs {0,1}+4k; half 1: {2,3}+4k
    const int l    = lane & 31;
    const int head = l >> 3;

    const float4 hd = ((const float4*)(h_dst + (size_t)node * DIM))[l];

    const float4 w0 = ((const float4*)W_attn)[4 * l + 0];
    const float4 w1 = ((const float4*)W_attn)[4 * l + 1];
    const float4 w2 = ((const float4*)W_attn)[4 * l + 2];
    const float4 w3 = ((const float4*)W_attn)[4 * l + 3];

    const int beg = offs[node];
    const int end = offs[node + 1];

    float4 acc = make_float4(0.f, 0.f, 0.f, 0.f);
    float  den = 0.f;

    for (int j = beg + 2 * half; j < end; j += 4) {
        const bool v1 = (j + 1 < end);
        const int s0 = srcs[j];
        const int s1 = srcs[v1 ? j + 1 : j];

        const float4 hs0 = ((const float4*)(h_src + (size_t)s0 * DIM))[l];
        const float4 hs1 = ((const float4*)(h_src + (size_t)s1 * DIM))[l];

        float b0 = hs0.x + hd.x; b0 = b0 > 0.f ? b0 : 0.2f * b0;
        float b1 = hs0.y + hd.y; b1 = b1 > 0.f ? b1 : 0.2f * b1;
        float b2 = hs0.z + hd.z; b2 = b2 > 0.f ? b2 : 0.2f * b2;
        float b3 = hs0.w + hd.w; b3 = b3 > 0.f ? b3 : 0.2f * b3;

        float c0 = hs1.x + hd.x; c0 = c0 > 0.f ? c0 : 0.2f * c0;
        float c1 = hs1.y + hd.y; c1 = c1 > 0.f ? c1 : 0.2f * c1;
        float c2 = hs1.z + hd.z; c2 = c2 > 0.f ? c2 : 0.2f * c2;
        float c3 = hs1.w + hd.w; c3 = c3 > 0.f ? c3 : 0.2f * c3;

        float px0 = b0 * w0.x + b1 * w1.x + b2 * w2.x + b3 * w3.x;
        float py0 = b0 * w0.y + b1 * w1.y + b2 * w2.y + b3 * w3.y;
        float pz0 = b0 * w0.z + b1 * w1.z + b2 * w2.z + b3 * w3.z;
        float pw0 = b0 * w0.w + b1 * w1.w + b2 * w2.w + b3 * w3.w;

        float px1 = c0 * w0.x + c1 * w1.x + c2 * w2.x + c3 * w3.x;
        float py1 = c0 * w0.y + c1 * w1.y + c2 * w2.y + c3 * w3.y;
        float pz1 = c0 * w0.z + c1 * w1.z + c2 * w2.z + c3 * w3.z;
        float pw1 = c0 * w0.w + c1 * w1.w + c2 * w2.w + c3 * w3.w;

        #pragma unroll
        for (int m = 16; m > 0; m >>= 1) {   // two independent chains interleave
            px0 += __shfl_xor(px0, m, 32);
            px1 += __shfl_xor(px1, m, 32);
            py0 += __shfl_xor(py0, m, 32);
            py1 += __shfl_xor(py1, m, 32);
            pz0 += __shfl_xor(pz0, m, 32);
            pz1 += __shfl_xor(pz1, m, 32);
            pw0 += __shfl_xor(pw0, m, 32);
            pw1 += __shfl_xor(pw1, m, 32);
        }

        const float ah0 = (head == 0) ? __expf(px0) :
                          (head == 1) ? __expf(py0) :
                          (head == 2) ? __expf(pz0) : __expf(pw0);
        float ah1       = (head == 0) ? __expf(px1) :
                          (head == 1) ? __expf(py1) :
                          (head == 2) ? __expf(pz1) : __expf(pw1);
        ah1 = v1 ? ah1 : 0.f;

        acc.x += ah0 * hs0.x + ah1 * hs1.x;
        acc.y += ah0 * hs0.y + ah1 * hs1.y;
        acc.z += ah0 * hs0.z + ah1 * hs1.z;
        acc.w += ah0 * hs0.w + ah1 * hs1.w;
        den   += ah0 + ah1;
    }

    acc.x += __shfl_xor(acc.x, 32, 64);
    acc.y += __shfl_xor(acc.y, 32, 64);
    acc.z += __shfl_xor(acc.z, 32, 64);
    acc.w += __shfl_xor(acc.w, 32, 64);
    den   += __shfl_xor(den,   32, 64);

    const float dinv = 1.0f / (den + 1e-9f);
    float4 o;
    o.x = acc.x * dinv + hd.x;
    o.y = acc.y * dinv + hd.y;
    o.z = acc.z * dinv + hd.z;
    o.w = acc.w * dinv + hd.w;

    float s1 = o.x + o.y + o.z + o.w;
    float s2 = o.x * o.x + o.y * o.y + o.z * o.z + o.w * o.w;
    #pragma unroll
    for (int m = 16; m > 0; m >>= 1) {
        s1 += __shfl_xor(s1, m, 32);
        s2 += __shfl_xor(s2, m, 32);
    }
    const float mu   = s1 * (1.0f / 128.0f);
    const float var  = s2 * (1.0f / 128.0f) - mu * mu;
    const float rstd = rsqrtf(var + 1e-5f);

    if (half == 0) {
        const float4 g = ((const float4*)gamma)[l];
        const float4 b = ((const float4*)beta)[l];
        float4 res;
        res.x = (o.x - mu) * rstd * g.x + b.x;
        res.y = (o.y - mu) * rstd * g.y + b.y;
        res.z = (o.z - mu) * rstd * g.z + b.z;
        res.w = (o.w - mu) * rstd * g.w + b.w;
        ((float4*)(out + (size_t)node * DIM))[l] = res;
    }
}

// ---------------------------------------------------------------------------
extern "C" void kernel_launch(void* const* d_in, const int* in_sizes, int n_in,
                              void* d_out, int out_size, void* d_ws, size_t ws_size,
                              hipStream_t stream)
{
    const float* x     = (const float*)d_in[0];
    const int*   ei    = (const int*)d_in[1];
    const float* Wsrc  = (const float*)d_in[2];
    const float* Wdst  = (const float*)d_in[3];
    const float* Wattn = (const float*)d_in[4];
    const float* gamma = (const float*)d_in[5];
    const float* beta  = (const float*)d_in[6];
    float* out = (float*)d_out;

    const int n = in_sizes[0] / DIM;
    const int E = in_sizes[1] / 2;
    const int nb = (n + 1023) / 1024;          // scan blocks (49 for n=50K)

    float* h_src = (float*)d_ws;                       // n*128 f32
    float* h_dst = h_src + (size_t)n * DIM;            // n*128 f32
    int*   deg    = (int*)(h_dst + (size_t)n * DIM);   // n
    int*   offs   = deg + n;                           // n+1
    int*   cursor = offs + n + 1;                      // n
    int*   srcs   = cursor + n;                        // E
    int*   exc    = srcs + E;                          // n
    int*   bsum   = exc + n;                           // nb

    hipMemsetAsync(deg, 0, (size_t)n * sizeof(int), stream);

    k_hist <<<(E + 255) / 256, 256, 0, stream>>>(ei, deg, E);
    k_scanA<<<nb, 1024, 0, stream>>>(deg, exc, bsum, n);
    k_scanB<<<1, 1024, 0, stream>>>(bsum, nb);
    k_scanC<<<(n + 255) / 256, 256, 0, stream>>>(exc, bsum, offs, cursor, n, E);
    k_scatter<<<(E + 255) / 256, 256, 0, stream>>>(ei, cursor, srcs, E);

    k_dual_gemm<<<(n + GROWS - 1) / GROWS, 256, 0, stream>>>(x, Wsrc, Wdst, h_src, h_dst, n);

    k_aggregate<<<(n + 3) / 4, 256, 0, stream>>>(
        offs, srcs, h_src, h_dst, Wattn, gamma, beta, out, n);
}

// Round 16
// 359.938 us; speedup vs baseline: 1.0169x; 1.0169x over previous
//
#include <hip/hip_runtime.h>
#include <hip/hip_bf16.h>
#include <math.h>

#define DIM 128
#define NHEADS 4
#define GROWS 16

__device__ __forceinline__ float bf2f(unsigned short u) {
    union { unsigned int i; float f; } v;
    v.i = ((unsigned int)u) << 16;
    return v.f;
}

// ---------------------------------------------------------------------------
// K1: h_src = x @ W_src (stored BF16 — round-15: halves agg gather bytes),
//     h_dst = x @ W_dst (fp32; residual path needs precision).
// 16 rows/block (measured neutral vs 8); unroll capped (round-4 spill lesson).
// ---------------------------------------------------------------------------
__global__ __launch_bounds__(256) void k_dual_gemm(
    const float* __restrict__ x,
    const float* __restrict__ Wsrc, const float* __restrict__ Wdst,
    unsigned short* __restrict__ h_srcb, float* __restrict__ h_dst, int n)
{
    __shared__ float xs[GROWS][DIM];
    const int tid = threadIdx.x;
    const int r0 = blockIdx.x * GROWS;
    #pragma unroll
    for (int k = 0; k < GROWS * 32 / 256; ++k) {     // 2 float4s per thread
        int idx = k * 256 + tid;                      // 0..511
        int r = idx >> 5, c4 = idx & 31;
        int row = r0 + r;
        float4 v = make_float4(0.f, 0.f, 0.f, 0.f);
        if (row < n) v = ((const float4*)(x + (size_t)row * DIM))[c4];
        ((float4*)xs[r])[c4] = v;
    }
    __syncthreads();

    const int c = tid & 127;
    const bool is_src = (tid < 128);
    const float* __restrict__ W = is_src ? Wsrc : Wdst;

    float acc[GROWS];
    #pragma unroll
    for (int r = 0; r < GROWS; ++r) acc[r] = 0.f;

    #pragma unroll 2
    for (int j4 = 0; j4 < DIM / 4; ++j4) {
        const float w0 = W[(4 * j4 + 0) * DIM + c];
        const float w1 = W[(4 * j4 + 1) * DIM + c];
        const float w2 = W[(4 * j4 + 2) * DIM + c];
        const float w3 = W[(4 * j4 + 3) * DIM + c];
        #pragma unroll
        for (int r = 0; r < GROWS; ++r) {
            const float4 xv = ((const float4*)xs[r])[j4];   // b128 broadcast
            acc[r] += xv.x * w0 + xv.y * w1 + xv.z * w2 + xv.w * w3;
        }
    }
    if (is_src) {
        #pragma unroll
        for (int r = 0; r < GROWS; ++r) {
            if (r0 + r < n) {
                __hip_bfloat16 b = __float2bfloat16(acc[r]);
                h_srcb[(size_t)(r0 + r) * DIM + c] = *(unsigned short*)&b;
            }
        }
    } else {
        #pragma unroll
        for (int r = 0; r < GROWS; ++r) {
            if (r0 + r < n) h_dst[(size_t)(r0 + r) * DIM + c] = acc[r];
        }
    }
}

// ---------------------------------------------------------------------------
// CSR build: histogram -> multi-block scan (A/B/C) -> scatter
// ---------------------------------------------------------------------------
__global__ __launch_bounds__(256) void k_hist(
    const int* __restrict__ ei, int* __restrict__ deg, int E)
{
    int e = blockIdx.x * 256 + threadIdx.x;
    if (e < E) atomicAdd(&deg[ei[E + e]], 1);
}

__global__ __launch_bounds__(1024) void k_scanA(
    const int* __restrict__ deg, int* __restrict__ exc,
    int* __restrict__ bsum, int n)
{
    __shared__ int buf[1024];
    const int t = threadIdx.x;
    const int i = blockIdx.x * 1024 + t;
    int v = (i < n) ? deg[i] : 0;
    buf[t] = v;
    __syncthreads();
    #pragma unroll
    for (int off = 1; off < 1024; off <<= 1) {
        int u = (t >= off) ? buf[t - off] : 0;
        __syncthreads();
        buf[t] += u;
        __syncthreads();
    }
    if (i < n) exc[i] = buf[t] - v;
    if (t == 1023) bsum[blockIdx.x] = buf[1023];
}

__global__ __launch_bounds__(1024) void k_scanB(int* __restrict__ bsum, int nb)
{
    __shared__ int buf[1024];
    const int t = threadIdx.x;
    int v = (t < nb) ? bsum[t] : 0;
    buf[t] = v;
    __syncthreads();
    #pragma unroll
    for (int off = 1; off < 1024; off <<= 1) {
        int u = (t >= off) ? buf[t - off] : 0;
        __syncthreads();
        buf[t] += u;
        __syncthreads();
    }
    if (t < nb) bsum[t] = buf[t] - v;
}

__global__ __launch_bounds__(256) void k_scanC(
    const int* __restrict__ exc, const int* __restrict__ bsum,
    int* __restrict__ offs, int* __restrict__ cursor, int n, int E)
{
    int i = blockIdx.x * 256 + threadIdx.x;
    if (i < n) {
        int o = exc[i] + bsum[i >> 10];
        offs[i] = o;
        cursor[i] = o;
    }
    if (i == 0) offs[n] = E;
}

__global__ __launch_bounds__(256) void k_scatter(
    const int* __restrict__ ei, int* __restrict__ cursor,
    int* __restrict__ srcs, int E)
{
    int e = blockIdx.x * 256 + threadIdx.x;
    if (e >= E) return;
    int s = ei[e];
    int d = ei[E + e];
    int pos = atomicAdd(&cursor[d], 1);
    srcs[pos] = s;
}

// ---------------------------------------------------------------------------
// K2: pull-mode aggregation + residual + LayerNorm. ROUND-15: reverted to the
// round-12 1-edge-per-half form (2-edge ILP cost occupancy 70->52%, net -4%).
// h_src gathered as bf16x4 (8B/lane) — halves the dominant gather traffic.
// Full-W_attn width-32 butterfly per edge (round-11 lesson).
// ---------------------------------------------------------------------------
__global__ __launch_bounds__(256) void k_aggregate(
    const int* __restrict__ offs, const int* __restrict__ srcs,
    const unsigned short* __restrict__ h_srcb, const float* __restrict__ h_dst,
    const float* __restrict__ W_attn,
    const float* __restrict__ gamma, const float* __restrict__ beta,
    float* __restrict__ out, int n)
{
    const int node = blockIdx.x * 4 + (threadIdx.x >> 6);
    if (node >= n) return;
    const int lane = threadIdx.x & 63;
    const int half = lane >> 5;       // 0: even edges, 1: odd edges
    const int l    = lane & 31;
    const int head = l >> 3;

    const float4 hd = ((const float4*)(h_dst + (size_t)node * DIM))[l];

    const float4 w0 = ((const float4*)W_attn)[4 * l + 0];
    const float4 w1 = ((const float4*)W_attn)[4 * l + 1];
    const float4 w2 = ((const float4*)W_attn)[4 * l + 2];
    const float4 w3 = ((const float4*)W_attn)[4 * l + 3];

    const int beg = offs[node];
    const int end = offs[node + 1];

    float4 acc = make_float4(0.f, 0.f, 0.f, 0.f);
    float  den = 0.f;

    for (int j = beg + half; j < end; j += 2) {
        const int s = srcs[j];
        const ushort4 hu = ((const ushort4*)(h_srcb + (size_t)s * DIM))[l];
        const float hx = bf2f(hu.x), hy = bf2f(hu.y),
                    hz = bf2f(hu.z), hw = bf2f(hu.w);

        float a0 = hx + hd.x; a0 = a0 > 0.f ? a0 : 0.2f * a0;
        float a1 = hy + hd.y; a1 = a1 > 0.f ? a1 : 0.2f * a1;
        float a2 = hz + hd.z; a2 = a2 > 0.f ? a2 : 0.2f * a2;
        float a3 = hw + hd.w; a3 = a3 > 0.f ? a3 : 0.2f * a3;

        float px = a0 * w0.x + a1 * w1.x + a2 * w2.x + a3 * w3.x;
        float py = a0 * w0.y + a1 * w1.y + a2 * w2.y + a3 * w3.y;
        float pz = a0 * w0.z + a1 * w1.z + a2 * w2.z + a3 * w3.z;
        float pw = a0 * w0.w + a1 * w1.w + a2 * w2.w + a3 * w3.w;

        #pragma unroll
        for (int m = 16; m > 0; m >>= 1) {   // width-32: stays inside this half
            px += __shfl_xor(px, m, 32);
            py += __shfl_xor(py, m, 32);
            pz += __shfl_xor(pz, m, 32);
            pw += __shfl_xor(pw, m, 32);
        }

        const float ah = (head == 0) ? __expf(px) :
                         (head == 1) ? __expf(py) :
                         (head == 2) ? __expf(pz) : __expf(pw);

        acc.x += ah * hx;
        acc.y += ah * hy;
        acc.z += ah * hz;
        acc.w += ah * hw;
        den   += ah;
    }

    acc.x += __shfl_xor(acc.x, 32, 64);
    acc.y += __shfl_xor(acc.y, 32, 64);
    acc.z += __shfl_xor(acc.z, 32, 64);
    acc.w += __shfl_xor(acc.w, 32, 64);
    den   += __shfl_xor(den,   32, 64);

    const float dinv = 1.0f / (den + 1e-9f);
    float4 o;
    o.x = acc.x * dinv + hd.x;
    o.y = acc.y * dinv + hd.y;
    o.z = acc.z * dinv + hd.z;
    o.w = acc.w * dinv + hd.w;

    float s1 = o.x + o.y + o.z + o.w;
    float s2 = o.x * o.x + o.y * o.y + o.z * o.z + o.w * o.w;
    #pragma unroll
    for (int m = 16; m > 0; m >>= 1) {
        s1 += __shfl_xor(s1, m, 32);
        s2 += __shfl_xor(s2, m, 32);
    }
    const float mu   = s1 * (1.0f / 128.0f);
    const float var  = s2 * (1.0f / 128.0f) - mu * mu;
    const float rstd = rsqrtf(var + 1e-5f);

    if (half == 0) {
        const float4 g = ((const float4*)gamma)[l];
        const float4 b = ((const float4*)beta)[l];
        float4 res;
        res.x = (o.x - mu) * rstd * g.x + b.x;
        res.y = (o.y - mu) * rstd * g.y + b.y;
        res.z = (o.z - mu) * rstd * g.z + b.z;
        res.w = (o.w - mu) * rstd * g.w + b.w;
        ((float4*)(out + (size_t)node * DIM))[l] = res;
    }
}

// ---------------------------------------------------------------------------
extern "C" void kernel_launch(void* const* d_in, const int* in_sizes, int n_in,
                              void* d_out, int out_size, void* d_ws, size_t ws_size,
                              hipStream_t stream)
{
    const float* x     = (const float*)d_in[0];
    const int*   ei    = (const int*)d_in[1];
    const float* Wsrc  = (const float*)d_in[2];
    const float* Wdst  = (const float*)d_in[3];
    const float* Wattn = (const float*)d_in[4];
    const float* gamma = (const float*)d_in[5];
    const float* beta  = (const float*)d_in[6];
    float* out = (float*)d_out;

    const int n = in_sizes[0] / DIM;
    const int E = in_sizes[1] / 2;
    const int nb = (n + 1023) / 1024;

    float*          h_dst  = (float*)d_ws;                        // n*128 f32
    unsigned short* h_srcb = (unsigned short*)(h_dst + (size_t)n * DIM); // n*128 bf16
    int*   deg    = (int*)(h_srcb + (size_t)n * DIM);             // n
    int*   offs   = deg + n;                                      // n+1
    int*   cursor = offs + n + 1;                                 // n
    int*   srcs   = cursor + n;                                   // E
    int*   exc    = srcs + E;                                     // n
    int*   bsum   = exc + n;                                      // nb

    hipMemsetAsync(deg, 0, (size_t)n * sizeof(int), stream);

    k_hist <<<(E + 255) / 256, 256, 0, stream>>>(ei, deg, E);
    k_scanA<<<nb, 1024, 0, stream>>>(deg, exc, bsum, n);
    k_scanB<<<1, 1024, 0, stream>>>(bsum, nb);
    k_scanC<<<(n + 255) / 256, 256, 0, stream>>>(exc, bsum, offs, cursor, n, E);
    k_scatter<<<(E + 255) / 256, 256, 0, stream>>>(ei, cursor, srcs, E);

    k_dual_gemm<<<(n + GROWS - 1) / GROWS, 256, 0, stream>>>(x, Wsrc, Wdst, h_srcb, h_dst, n);

    k_aggregate<<<(n + 3) / 4, 256, 0, stream>>>(
        offs, srcs, h_srcb, h_dst, Wattn, gamma, beta, out, n);
}

// Round 17
// 313.469 us; speedup vs baseline: 1.1676x; 1.1482x over previous
//
#include <hip/hip_runtime.h>
#include <hip/hip_bf16.h>
#include <math.h>

#define DIM 128
#define NHEADS 4
#define GROWS 16

__device__ __forceinline__ float bf2f(unsigned short u) {
    union { unsigned int i; float f; } v;
    v.i = ((unsigned int)u) << 16;
    return v.f;
}

// ---------------------------------------------------------------------------
// K1: h_src = x @ W_src (bf16 out), h_dst = x @ W_dst (f32 out).
// round-16 re-block: TM=4 x TN=4 per thread (was TM=16,TN=1) — LDS b128
// reads per thread 512 -> 128 (kernel was LDS-read-throughput-bound).
// ty = tid>>6 owns 4 rows; tx = tid&63 owns 4 consecutive cols
// (lanes 0-31 -> Wsrc, 32-63 -> Wdst). W loads float4, fully coalesced.
// ---------------------------------------------------------------------------
__global__ __launch_bounds__(256) void k_dual_gemm(
    const float* __restrict__ x,
    const float* __restrict__ Wsrc, const float* __restrict__ Wdst,
    unsigned short* __restrict__ h_srcb, float* __restrict__ h_dst, int n)
{
    __shared__ float xs[GROWS][DIM];
    const int tid = threadIdx.x;
    const int r0 = blockIdx.x * GROWS;
    #pragma unroll
    for (int k = 0; k < 2; ++k) {                 // 512 float4 by 256 threads
        int idx = k * 256 + tid;
        int r = idx >> 5, c4 = idx & 31;
        int row = r0 + r;
        float4 v = make_float4(0.f, 0.f, 0.f, 0.f);
        if (row < n) v = ((const float4*)(x + (size_t)row * DIM))[c4];
        ((float4*)xs[r])[c4] = v;
    }
    __syncthreads();

    const int tx = tid & 63;                      // col-thread (lane)
    const int ty = tid >> 6;                      // row-group 0..3
    const bool is_src = (tx < 32);
    const float* __restrict__ W = is_src ? Wsrc : Wdst;
    const int c = (tx & 31) * 4;                  // 4 consecutive columns

    float4 acc0 = make_float4(0.f,0.f,0.f,0.f);
    float4 acc1 = make_float4(0.f,0.f,0.f,0.f);
    float4 acc2 = make_float4(0.f,0.f,0.f,0.f);
    float4 acc3 = make_float4(0.f,0.f,0.f,0.f);

    #pragma unroll 2
    for (int j4 = 0; j4 < DIM / 4; ++j4) {
        const float4 wv0 = *(const float4*)(W + (4*j4+0)*DIM + c);
        const float4 wv1 = *(const float4*)(W + (4*j4+1)*DIM + c);
        const float4 wv2 = *(const float4*)(W + (4*j4+2)*DIM + c);
        const float4 wv3 = *(const float4*)(W + (4*j4+3)*DIM + c);

        const float4 xv0 = ((const float4*)xs[ty*4+0])[j4];
        const float4 xv1 = ((const float4*)xs[ty*4+1])[j4];
        const float4 xv2 = ((const float4*)xs[ty*4+2])[j4];
        const float4 xv3 = ((const float4*)xs[ty*4+3])[j4];

        acc0.x += xv0.x*wv0.x + xv0.y*wv1.x + xv0.z*wv2.x + xv0.w*wv3.x;
        acc0.y += xv0.x*wv0.y + xv0.y*wv1.y + xv0.z*wv2.y + xv0.w*wv3.y;
        acc0.z += xv0.x*wv0.z + xv0.y*wv1.z + xv0.z*wv2.z + xv0.w*wv3.z;
        acc0.w += xv0.x*wv0.w + xv0.y*wv1.w + xv0.z*wv2.w + xv0.w*wv3.w;

        acc1.x += xv1.x*wv0.x + xv1.y*wv1.x + xv1.z*wv2.x + xv1.w*wv3.x;
        acc1.y += xv1.x*wv0.y + xv1.y*wv1.y + xv1.z*wv2.y + xv1.w*wv3.y;
        acc1.z += xv1.x*wv0.z + xv1.y*wv1.z + xv1.z*wv2.z + xv1.w*wv3.z;
        acc1.w += xv1.x*wv0.w + xv1.y*wv1.w + xv1.z*wv2.w + xv1.w*wv3.w;

        acc2.x += xv2.x*wv0.x + xv2.y*wv1.x + xv2.z*wv2.x + xv2.w*wv3.x;
        acc2.y += xv2.x*wv0.y + xv2.y*wv1.y + xv2.z*wv2.y + xv2.w*wv3.y;
        acc2.z += xv2.x*wv0.z + xv2.y*wv1.z + xv2.z*wv2.z + xv2.w*wv3.z;
        acc2.w += xv2.x*wv0.w + xv2.y*wv1.w + xv2.z*wv2.w + xv2.w*wv3.w;

        acc3.x += xv3.x*wv0.x + xv3.y*wv1.x + xv3.z*wv2.x + xv3.w*wv3.x;
        acc3.y += xv3.x*wv0.y + xv3.y*wv1.y + xv3.z*wv2.y + xv3.w*wv3.y;
        acc3.z += xv3.x*wv0.z + xv3.y*wv1.z + xv3.z*wv2.z + xv3.w*wv3.z;
        acc3.w += xv3.x*wv0.w + xv3.y*wv1.w + xv3.z*wv2.w + xv3.w*wv3.w;
    }

    #pragma unroll
    for (int rr = 0; rr < 4; ++rr) {
        const int row = r0 + ty * 4 + rr;
        if (row >= n) continue;
        const float4 a = (rr == 0) ? acc0 : (rr == 1) ? acc1 : (rr == 2) ? acc2 : acc3;
        if (is_src) {
            __hip_bfloat16 b0 = __float2bfloat16(a.x);
            __hip_bfloat16 b1 = __float2bfloat16(a.y);
            __hip_bfloat16 b2 = __float2bfloat16(a.z);
            __hip_bfloat16 b3 = __float2bfloat16(a.w);
            ushort4 u;
            u.x = *(unsigned short*)&b0; u.y = *(unsigned short*)&b1;
            u.z = *(unsigned short*)&b2; u.w = *(unsigned short*)&b3;
            *(ushort4*)(h_srcb + (size_t)row * DIM + c) = u;
        } else {
            *(float4*)(h_dst + (size_t)row * DIM + c) = a;
        }
    }
}

// ---------------------------------------------------------------------------
// CSR build: histogram -> multi-block scan (A/B/C) -> scatter
// ---------------------------------------------------------------------------
__global__ __launch_bounds__(256) void k_hist(
    const int* __restrict__ ei, int* __restrict__ deg, int E)
{
    int e = blockIdx.x * 256 + threadIdx.x;
    if (e < E) atomicAdd(&deg[ei[E + e]], 1);
}

__global__ __launch_bounds__(1024) void k_scanA(
    const int* __restrict__ deg, int* __restrict__ exc,
    int* __restrict__ bsum, int n)
{
    __shared__ int buf[1024];
    const int t = threadIdx.x;
    const int i = blockIdx.x * 1024 + t;
    int v = (i < n) ? deg[i] : 0;
    buf[t] = v;
    __syncthreads();
    #pragma unroll
    for (int off = 1; off < 1024; off <<= 1) {
        int u = (t >= off) ? buf[t - off] : 0;
        __syncthreads();
        buf[t] += u;
        __syncthreads();
    }
    if (i < n) exc[i] = buf[t] - v;
    if (t == 1023) bsum[blockIdx.x] = buf[1023];
}

__global__ __launch_bounds__(1024) void k_scanB(int* __restrict__ bsum, int nb)
{
    __shared__ int buf[1024];
    const int t = threadIdx.x;
    int v = (t < nb) ? bsum[t] : 0;
    buf[t] = v;
    __syncthreads();
    #pragma unroll
    for (int off = 1; off < 1024; off <<= 1) {
        int u = (t >= off) ? buf[t - off] : 0;
        __syncthreads();
        buf[t] += u;
        __syncthreads();
    }
    if (t < nb) bsum[t] = buf[t] - v;
}

__global__ __launch_bounds__(256) void k_scanC(
    const int* __restrict__ exc, const int* __restrict__ bsum,
    int* __restrict__ offs, int* __restrict__ cursor, int n, int E)
{
    int i = blockIdx.x * 256 + threadIdx.x;
    if (i < n) {
        int o = exc[i] + bsum[i >> 10];
        offs[i] = o;
        cursor[i] = o;
    }
    if (i == 0) offs[n] = E;
}

__global__ __launch_bounds__(256) void k_scatter(
    const int* __restrict__ ei, int* __restrict__ cursor,
    int* __restrict__ srcs, int E)
{
    int e = blockIdx.x * 256 + threadIdx.x;
    if (e >= E) return;
    int s = ei[e];
    int d = ei[E + e];
    int pos = atomicAdd(&cursor[d], 1);
    srcs[pos] = s;
}

// ---------------------------------------------------------------------------
// K2: pull-mode aggregation + residual + LayerNorm. 1 edge/half (round-15:
// 2-edge ILP lost to occupancy). round-16: attention reduce restructured from
// 20-shfl butterfly to transpose-reduce: 2 pair-merges (xor1/xor2) fold the
// 4 head-chains to 1 value/lane (color = l&3), 3-step butterfly (xor 4/8/16),
// then 1 index-shfl broadcast. 7 shfls/edge total. Full 128-feature dot per
// head preserved (round-11 lesson).
// ---------------------------------------------------------------------------
__global__ __launch_bounds__(256) void k_aggregate(
    const int* __restrict__ offs, const int* __restrict__ srcs,
    const unsigned short* __restrict__ h_srcb, const float* __restrict__ h_dst,
    const float* __restrict__ W_attn,
    const float* __restrict__ gamma, const float* __restrict__ beta,
    float* __restrict__ out, int n)
{
    const int node = blockIdx.x * 4 + (threadIdx.x >> 6);
    if (node >= n) return;
    const int lane = threadIdx.x & 63;
    const int half = lane >> 5;       // 0: even edges, 1: odd edges
    const int l    = lane & 31;
    const int head = l >> 3;

    const float4 hd = ((const float4*)(h_dst + (size_t)node * DIM))[l];

    const float4 w0 = ((const float4*)W_attn)[4 * l + 0];
    const float4 w1 = ((const float4*)W_attn)[4 * l + 1];
    const float4 w2 = ((const float4*)W_attn)[4 * l + 2];
    const float4 w3 = ((const float4*)W_attn)[4 * l + 3];

    const int beg = offs[node];
    const int end = offs[node + 1];

    float4 acc = make_float4(0.f, 0.f, 0.f, 0.f);
    float  den = 0.f;

    for (int j = beg + half; j < end; j += 2) {
        const int s = srcs[j];
        const ushort4 hu = ((const ushort4*)(h_srcb + (size_t)s * DIM))[l];
        const float hx = bf2f(hu.x), hy = bf2f(hu.y),
                    hz = bf2f(hu.z), hw = bf2f(hu.w);

        float a0 = hx + hd.x; a0 = a0 > 0.f ? a0 : 0.2f * a0;
        float a1 = hy + hd.y; a1 = a1 > 0.f ? a1 : 0.2f * a1;
        float a2 = hz + hd.z; a2 = a2 > 0.f ? a2 : 0.2f * a2;
        float a3 = hw + hd.w; a3 = a3 > 0.f ? a3 : 0.2f * a3;

        float px = a0 * w0.x + a1 * w1.x + a2 * w2.x + a3 * w3.x;
        float py = a0 * w0.y + a1 * w1.y + a2 * w2.y + a3 * w3.y;
        float pz = a0 * w0.z + a1 * w1.z + a2 * w2.z + a3 * w3.z;
        float pw = a0 * w0.w + a1 * w1.w + a2 * w2.w + a3 * w3.w;

        // --- transpose-reduce: 7 shfls total ---
        // step1 (xor1): fold px/py and pz/pw; even lane keeps px/pz, odd py/pw
        const bool b0_ = (l & 1);
        float A = b0_ ? py : px;
        A += __shfl_xor(b0_ ? px : py, 1, 32);
        float B = b0_ ? pw : pz;
        B += __shfl_xor(b0_ ? pz : pw, 1, 32);
        // step2 (xor2): fold A/B; bit1=0 keeps A, bit1=1 keeps B
        const bool b1_ = (l & 2);
        float Cv = b1_ ? B : A;
        Cv += __shfl_xor(b1_ ? A : B, 2, 32);
        // now color l&3: 0->h0, 1->h1, 2->h2, 3->h3 (summed over lane-quad)
        Cv += __shfl_xor(Cv, 4, 32);
        Cv += __shfl_xor(Cv, 8, 32);
        Cv += __shfl_xor(Cv, 16, 32);
        // every lane: pick its head's full 32-lane sum
        const float Sh = __shfl(Cv, head, 32);

        const float ah = __expf(Sh);

        acc.x += ah * hx;
        acc.y += ah * hy;
        acc.z += ah * hz;
        acc.w += ah * hw;
        den   += ah;
    }

    acc.x += __shfl_xor(acc.x, 32, 64);
    acc.y += __shfl_xor(acc.y, 32, 64);
    acc.z += __shfl_xor(acc.z, 32, 64);
    acc.w += __shfl_xor(acc.w, 32, 64);
    den   += __shfl_xor(den,   32, 64);

    const float dinv = 1.0f / (den + 1e-9f);
    float4 o;
    o.x = acc.x * dinv + hd.x;
    o.y = acc.y * dinv + hd.y;
    o.z = acc.z * dinv + hd.z;
    o.w = acc.w * dinv + hd.w;

    float s1 = o.x + o.y + o.z + o.w;
    float s2 = o.x * o.x + o.y * o.y + o.z * o.z + o.w * o.w;
    #pragma unroll
    for (int m = 16; m > 0; m >>= 1) {
        s1 += __shfl_xor(s1, m, 32);
        s2 += __shfl_xor(s2, m, 32);
    }
    const float mu   = s1 * (1.0f / 128.0f);
    const float var  = s2 * (1.0f / 128.0f) - mu * mu;
    const float rstd = rsqrtf(var + 1e-5f);

    if (half == 0) {
        const float4 g = ((const float4*)gamma)[l];
        const float4 b = ((const float4*)beta)[l];
        float4 res;
        res.x = (o.x - mu) * rstd * g.x + b.x;
        res.y = (o.y - mu) * rstd * g.y + b.y;
        res.z = (o.z - mu) * rstd * g.z + b.z;
        res.w = (o.w - mu) * rstd * g.w + b.w;
        ((float4*)(out + (size_t)node * DIM))[l] = res;
    }
}

// ---------------------------------------------------------------------------
extern "C" void kernel_launch(void* const* d_in, const int* in_sizes, int n_in,
                              void* d_out, int out_size, void* d_ws, size_t ws_size,
                              hipStream_t stream)
{
    const float* x     = (const float*)d_in[0];
    const int*   ei    = (const int*)d_in[1];
    const float* Wsrc  = (const float*)d_in[2];
    const float* Wdst  = (const float*)d_in[3];
    const float* Wattn = (const float*)d_in[4];
    const float* gamma = (const float*)d_in[5];
    const float* beta  = (const float*)d_in[6];
    float* out = (float*)d_out;

    const int n = in_sizes[0] / DIM;
    const int E = in_sizes[1] / 2;
    const int nb = (n + 1023) / 1024;

    float*          h_dst  = (float*)d_ws;                        // n*128 f32
    unsigned short* h_srcb = (unsigned short*)(h_dst + (size_t)n * DIM); // n*128 bf16
    int*   deg    = (int*)(h_srcb + (size_t)n * DIM);             // n
    int*   offs   = deg + n;                                      // n+1
    int*   cursor = offs + n + 1;                                 // n
    int*   srcs   = cursor + n;                                   // E
    int*   exc    = srcs + E;                                     // n
    int*   bsum   = exc + n;                                      // nb

    hipMemsetAsync(deg, 0, (size_t)n * sizeof(int), stream);

    k_hist <<<(E + 255) / 256, 256, 0, stream>>>(ei, deg, E);
    k_scanA<<<nb, 1024, 0, stream>>>(deg, exc, bsum, n);
    k_scanB<<<1, 1024, 0, stream>>>(bsum, nb);
    k_scanC<<<(n + 255) / 256, 256, 0, stream>>>(exc, bsum, offs, cursor, n, E);
    k_scatter<<<(E + 255) / 256, 256, 0, stream>>>(ei, cursor, srcs, E);

    k_dual_gemm<<<(n + GROWS - 1) / GROWS, 256, 0, stream>>>(x, Wsrc, Wdst, h_srcb, h_dst, n);

    k_aggregate<<<(n + 3) / 4, 256, 0, stream>>>(
        offs, srcs, h_srcb, h_dst, Wattn, gamma, beta, out, n);
}